// Round 2
// baseline (669.644 us; speedup 1.0000x reference)
//
#include <hip/hip_runtime.h>
#include <math.h>

#define NROWS 4096
#define DIM   256
#define HALF_MASK 2047
#define R 4
#define BLOCK 256

// order-preserving float -> uint transform (ascending uint == ascending float)
__device__ __forceinline__ unsigned fkey(float f) {
    unsigned u = __float_as_uint(f);
    return (u & 0x80000000u) ? ~u : (u | 0x80000000u);
}

// ---------------------------------------------------------------------------
// prep: L2-normalize rows, sq[j] = sum(fn^2), labels packed to bytes
// ---------------------------------------------------------------------------
__global__ void prep_kernel(const float* __restrict__ feat,
                            const int* __restrict__ labels,
                            float* __restrict__ fn,
                            float* __restrict__ sq,
                            unsigned char* __restrict__ lab8,
                            float* __restrict__ out)
{
    const int row  = blockIdx.x * 4 + (threadIdx.x >> 6);
    const int lane = threadIdx.x & 63;
    float4 x = ((const float4*)feat)[(size_t)row * 64 + lane];
    float ss = x.x*x.x + x.y*x.y + x.z*x.z + x.w*x.w;
    #pragma unroll
    for (int m = 1; m < 64; m <<= 1) ss += __shfl_xor(ss, m, 64);
    const float nrm = sqrtf(ss);
    float4 f; f.x = x.x/nrm; f.y = x.y/nrm; f.z = x.z/nrm; f.w = x.w/nrm;
    ((float4*)fn)[(size_t)row * 64 + lane] = f;
    float s2 = f.x*f.x + f.y*f.y + f.z*f.z + f.w*f.w;
    #pragma unroll
    for (int m = 1; m < 64; m <<= 1) s2 += __shfl_xor(s2, m, 64);
    if (lane == 0) {
        sq[row]  = s2;
        lab8[row] = (unsigned char)labels[row & HALF_MASK];
    }
    if (blockIdx.x == 0 && threadIdx.x == 0) out[0] = 0.0f;
}

// ---------------------------------------------------------------------------
// rowloss: one block = 4 anchor rows; thread t owns columns [16t, 16t+16)
// all per-column dots live in registers (ALL r-indices static -> no scratch)
// ---------------------------------------------------------------------------
__global__ __launch_bounds__(BLOCK, 3) void rowloss_kernel(
        const float* __restrict__ fn,
        const float* __restrict__ sq,
        const unsigned char* __restrict__ lab8,
        float* __restrict__ out)
{
    __shared__ __align__(16) float fi[R][DIM];     // 4 KB anchor rows
    __shared__ unsigned hist[R * 256];             // 4 KB batched histograms
    __shared__ float    wz[R][4];
    __shared__ unsigned wsc[R][4];
    __shared__ unsigned selT[R], selK[R];
    __shared__ float    wsd[R][4];
    __shared__ int      wcnt[R][4];

    const int tid  = threadIdx.x;
    const int lane = tid & 63;
    const int wv   = tid >> 6;
    const int i0   = blockIdx.x * R;
    const int j0   = tid * 16;

    for (int idx = tid; idx < R * DIM; idx += BLOCK)
        fi[idx >> 8][idx & 255] = fn[(size_t)i0 * DIM + idx];
    __syncthreads();

    const float4* fn4 = (const float4*)fn;
    const float4* fi4 = (const float4*)&fi[0][0];

    // ---- phase A: dots for 16 columns x 4 rows, fully in registers ----
    float acc[16][R];
    #pragma unroll
    for (int jj = 0; jj < 16; ++jj)
        #pragma unroll
        for (int r = 0; r < R; ++r) acc[jj][r] = 0.0f;

    for (int c = 0; c < 32; ++c) {                 // 8 floats of d per chunk
        float fir[R][8];
        #pragma unroll
        for (int r = 0; r < R; ++r) {
            float4 a = fi4[r * 64 + c * 2];
            float4 b = fi4[r * 64 + c * 2 + 1];
            fir[r][0] = a.x; fir[r][1] = a.y; fir[r][2] = a.z; fir[r][3] = a.w;
            fir[r][4] = b.x; fir[r][5] = b.y; fir[r][6] = b.z; fir[r][7] = b.w;
        }
        #pragma unroll
        for (int jj = 0; jj < 16; ++jj) {
            const float4* p = fn4 + (size_t)(j0 + jj) * 64 + c * 2;
            float4 x = p[0];
            float4 y = p[1];
            #pragma unroll
            for (int r = 0; r < R; ++r) {
                float s = acc[jj][r];
                s = fmaf(x.x, fir[r][0], s); s = fmaf(x.y, fir[r][1], s);
                s = fmaf(x.z, fir[r][2], s); s = fmaf(x.w, fir[r][3], s);
                s = fmaf(y.x, fir[r][4], s); s = fmaf(y.y, fir[r][5], s);
                s = fmaf(y.z, fir[r][6], s); s = fmaf(y.w, fir[r][7], s);
                acc[jj][r] = s;
            }
        }
    }

    float sqr[16];
    #pragma unroll
    for (int k = 0; k < 16; ++k) sqr[k] = sq[j0 + k];

    // ---- Z = sum_{j != i} exp(10*dot); max-shift cancels algebraically ----
    float lzr[R];
    {
        float zloc[R];
        #pragma unroll
        for (int r = 0; r < R; ++r) {
            const int ir = i0 + r;
            float z = 0.0f;
            #pragma unroll
            for (int k = 0; k < 16; ++k) {
                float e = __expf(10.0f * acc[k][r]);
                z += (j0 + k == ir) ? 0.0f : e;
            }
            zloc[r] = z;
        }
        #pragma unroll
        for (int r = 0; r < R; ++r) {
            float z = zloc[r];
            #pragma unroll
            for (int m = 1; m < 64; m <<= 1) z += __shfl_xor(z, m, 64);
            if (lane == 0) wz[r][wv] = z;
        }
        __syncthreads();
        #pragma unroll
        for (int r = 0; r < R; ++r)
            lzr[r] = __logf(wz[r][0] + wz[r][1] + wz[r][2] + wz[r][3]);
    }

    // ---- radix-select the 128th-largest key, 4 rows simultaneously ----
    unsigned Pr[R] = {0, 0, 0, 0};
    unsigned Kr[R] = {128u, 128u, 128u, 128u};
    #pragma unroll
    for (int pass = 0; pass < 4; ++pass) {
        const int shift = 24 - 8 * pass;
        #pragma unroll
        for (int r = 0; r < R; ++r) hist[r * 256 + tid] = 0u;
        __syncthreads();
        #pragma unroll
        for (int r = 0; r < R; ++r) {
            #pragma unroll
            for (int k = 0; k < 16; ++k) {
                unsigned u = fkey(fmaf(-2.0f, acc[k][r], sqr[k]));
                bool act = (pass == 0) ||
                    (((unsigned long long)(u ^ Pr[r]) >> (shift + 8)) == 0ull);
                if (act) atomicAdd(&hist[r * 256 + ((u >> shift) & 255u)], 1u);
            }
        }
        __syncthreads();
        // suffix-sum via reversed prefix scan: thread tid <-> bin 255-tid
        unsigned g[R], P[R];
        #pragma unroll
        for (int r = 0; r < R; ++r) { g[r] = hist[r * 256 + (255 - tid)]; P[r] = g[r]; }
        #pragma unroll
        for (int d = 1; d < 64; d <<= 1) {
            #pragma unroll
            for (int r = 0; r < R; ++r) {
                unsigned o = __shfl_up(P[r], d, 64);
                if (lane >= d) P[r] += o;
            }
        }
        if (lane == 63) {
            #pragma unroll
            for (int r = 0; r < R; ++r) wsc[r][wv] = P[r];
        }
        __syncthreads();
        #pragma unroll
        for (int r = 0; r < R; ++r) {
            unsigned off = 0;
            #pragma unroll
            for (int w = 0; w < 4; ++w) if (w < wv) off += wsc[r][w];
            const unsigned Sv = P[r] + off;
            const unsigned Sn = Sv - g[r];
            if (Sv >= Kr[r] && Sn < Kr[r]) {
                selT[r] = Pr[r] | ((unsigned)(255 - tid) << shift);
                selK[r] = Kr[r] - Sn;
            }
        }
        __syncthreads();
        #pragma unroll
        for (int r = 0; r < R; ++r) { Pr[r] = selT[r]; Kr[r] = selK[r]; }
        __syncthreads();
    }

    // ---- tie ranks: exclusive prefix of per-thread tie counts, 4 rows ----
    int tb[R];
    {
        int tc[R], Pt[R];
        #pragma unroll
        for (int r = 0; r < R; ++r) {
            int c = 0;
            #pragma unroll
            for (int k = 0; k < 16; ++k)
                if (fkey(fmaf(-2.0f, acc[k][r], sqr[k])) == Pr[r]) c++;
            tc[r] = c; Pt[r] = c;
        }
        #pragma unroll
        for (int d = 1; d < 64; d <<= 1) {
            #pragma unroll
            for (int r = 0; r < R; ++r) {
                int o = __shfl_up(Pt[r], d, 64);
                if (lane >= d) Pt[r] += o;
            }
        }
        if (lane == 63) {
            #pragma unroll
            for (int r = 0; r < R; ++r) wsc[r][wv] = (unsigned)Pt[r];
        }
        __syncthreads();
        #pragma unroll
        for (int r = 0; r < R; ++r) {
            int off = 0;
            #pragma unroll
            for (int w = 0; w < 4; ++w) if (w < wv) off += (int)wsc[r][w];
            tb[r] = Pt[r] + off - tc[r];
        }
    }

    // ---- accumulate over selected & same-class ----
    const uint4 labv = ((const uint4*)lab8)[tid];
    const unsigned labw[4] = {labv.x, labv.y, labv.z, labv.w};

    #pragma unroll
    for (int r = 0; r < R; ++r) {
        const int ir = i0 + r;
        const unsigned my = lab8[ir];
        float sd = 0.0f; int cnt = 0; int t = tb[r];
        #pragma unroll
        for (int k = 0; k < 16; ++k) {
            const unsigned u = fkey(fmaf(-2.0f, acc[k][r], sqr[k]));
            bool sel = (u > Pr[r]);
            if (u == Pr[r]) { sel = (t < (int)Kr[r]); t++; }
            const unsigned lj = (labw[k >> 2] >> ((k & 3) * 8)) & 255u;
            if (sel && (j0 + k != ir) && lj == my) { cnt++; sd += acc[k][r]; }
        }
        #pragma unroll
        for (int m = 1; m < 64; m <<= 1) {
            sd  += __shfl_xor(sd, m, 64);
            cnt += __shfl_xor(cnt, m, 64);
        }
        if (lane == 0) { wsd[r][wv] = sd; wcnt[r][wv] = cnt; }
    }
    __syncthreads();

    if (tid < R) {
        const int r = tid;
        const int c = wcnt[r][0] + wcnt[r][1] + wcnt[r][2] + wcnt[r][3];
        if (c > 0) {
            const float sd = wsd[r][0] + wsd[r][1] + wsd[r][2] + wsd[r][3];
            const float mlpp = (10.0f * sd) / (float)c - lzr[r];
            atomicAdd(out, -(0.1f / 0.07f) * mlpp * (1.0f / (float)NROWS));
        }
    }
}

extern "C" void kernel_launch(void* const* d_in, const int* in_sizes, int n_in,
                              void* d_out, int out_size, void* d_ws, size_t ws_size,
                              hipStream_t stream) {
    (void)in_sizes; (void)n_in; (void)out_size; (void)ws_size;
    const float* feat  = (const float*)d_in[0];
    const int* labels  = (const int*)d_in[1];
    float* out = (float*)d_out;

    float* fn = (float*)d_ws;                          // 4096*256 floats = 4 MB
    float* sq = fn + (size_t)NROWS * DIM;              // 4096 floats
    unsigned char* lab8 = (unsigned char*)(sq + NROWS);// 4096 bytes (16B aligned)

    prep_kernel<<<NROWS / 4, BLOCK, 0, stream>>>(feat, labels, fn, sq, lab8, out);
    rowloss_kernel<<<NROWS / R, BLOCK, 0, stream>>>(fn, sq, lab8, out);
}

// Round 3
// 122.706 us; speedup vs baseline: 5.4573x; 5.4573x over previous
//
#include <hip/hip_runtime.h>
#include <hip/hip_bf16.h>
#include <math.h>

#define NROWS 4096
#define DIM   256
#define HALF_MASK 2047
#define BLOCK 256

typedef __attribute__((ext_vector_type(8))) short bf16x8;
typedef __attribute__((ext_vector_type(4))) float f32x4;

// order-preserving float -> uint transform (ascending uint == ascending float)
__device__ __forceinline__ unsigned fkey(float f) {
    unsigned u = __float_as_uint(f);
    return (u & 0x80000000u) ? ~u : (u | 0x80000000u);
}

// ===========================================================================
// FAST PATH (needs ~68 MB of d_ws): prep -> bf16 MFMA Gram -> per-row select
// ===========================================================================

// prep: L2-normalize rows -> bf16 fn, fp32 sq, byte labels, zero out
__global__ void prep_bf16_kernel(const float* __restrict__ feat,
                                 const int* __restrict__ labels,
                                 short* __restrict__ fnb,
                                 float* __restrict__ sq,
                                 unsigned char* __restrict__ lab8,
                                 float* __restrict__ out)
{
    const int row  = blockIdx.x * 4 + (threadIdx.x >> 6);
    const int lane = threadIdx.x & 63;
    float4 x = ((const float4*)feat)[(size_t)row * 64 + lane];
    float ss = x.x*x.x + x.y*x.y + x.z*x.z + x.w*x.w;
    #pragma unroll
    for (int m = 1; m < 64; m <<= 1) ss += __shfl_xor(ss, m, 64);
    const float nrm = sqrtf(ss);
    float4 f; f.x = x.x/nrm; f.y = x.y/nrm; f.z = x.z/nrm; f.w = x.w/nrm;

    union { __hip_bfloat16 b; unsigned short s; } cv[4];
    cv[0].b = __float2bfloat16(f.x); cv[1].b = __float2bfloat16(f.y);
    cv[2].b = __float2bfloat16(f.z); cv[3].b = __float2bfloat16(f.w);
    ushort4 h; h.x = cv[0].s; h.y = cv[1].s; h.z = cv[2].s; h.w = cv[3].s;
    ((ushort4*)fnb)[(size_t)row * 64 + lane] = h;

    float s2 = f.x*f.x + f.y*f.y + f.z*f.z + f.w*f.w;
    #pragma unroll
    for (int m = 1; m < 64; m <<= 1) s2 += __shfl_xor(s2, m, 64);
    if (lane == 0) {
        sq[row]   = s2;
        lab8[row] = (unsigned char)labels[row & HALF_MASK];
    }
    if (blockIdx.x == 0 && threadIdx.x == 0) out[0] = 0.0f;
}

// Gram: S = fn * fn^T  (4096x4096, K=256), bf16 MFMA 16x16x32, fp32 out.
// 128x128 tile, 4 waves (2x2), wave tile 64x64 = 4x4 frags of 16x16.
// LDS tiles XOR-swizzled (chunk ^= row&7) so frag ds_read_b128 is 2-way only.
__global__ __launch_bounds__(256) void gram_kernel(
        const short* __restrict__ fnb, float* __restrict__ S)
{
    __shared__ __align__(16) short As[128 * 64];
    __shared__ __align__(16) short Bs[128 * 64];

    const int tid  = threadIdx.x;
    const int lane = tid & 63;
    const int wv   = tid >> 6;
    const int wm   = wv >> 1, wn = wv & 1;
    const int bi   = blockIdx.x >> 5;
    const int bj   = blockIdx.x & 31;
    const int i0   = bi * 128, j0 = bj * 128;

    f32x4 acc[4][4];
    const f32x4 zero = {0.f, 0.f, 0.f, 0.f};
    #pragma unroll
    for (int a = 0; a < 4; ++a)
        #pragma unroll
        for (int b = 0; b < 4; ++b) acc[a][b] = zero;

    const int srow   = tid >> 3;   // 0..31
    const int schunk = tid & 7;    // 0..7 (16B chunks of a 128B k-row)

    for (int kt = 0; kt < 4; ++kt) {         // K tiles of 64
        #pragma unroll
        for (int is = 0; is < 4; ++is) {
            const int row = is * 32 + srow;
            const size_t gsrc = (size_t)kt * 64 + schunk * 8;
            uint4 va = *(const uint4*)(fnb + (size_t)(i0 + row) * DIM + gsrc);
            uint4 vb = *(const uint4*)(fnb + (size_t)(j0 + row) * DIM + gsrc);
            const int dst = row * 64 + ((schunk ^ (row & 7)) * 8);
            *(uint4*)(As + dst) = va;
            *(uint4*)(Bs + dst) = vb;
        }
        __syncthreads();
        #pragma unroll
        for (int kk = 0; kk < 2; ++kk) {
            bf16x8 af[4], bfr[4];
            #pragma unroll
            for (int mi = 0; mi < 4; ++mi) {
                const int row = wm * 64 + mi * 16 + (lane & 15);
                const int ch  = kk * 4 + (lane >> 4);
                af[mi] = *(const bf16x8*)(As + row * 64 + ((ch ^ (row & 7)) * 8));
            }
            #pragma unroll
            for (int ni = 0; ni < 4; ++ni) {
                const int row = wn * 64 + ni * 16 + (lane & 15);
                const int ch  = kk * 4 + (lane >> 4);
                bfr[ni] = *(const bf16x8*)(Bs + row * 64 + ((ch ^ (row & 7)) * 8));
            }
            #pragma unroll
            for (int mi = 0; mi < 4; ++mi)
                #pragma unroll
                for (int ni = 0; ni < 4; ++ni)
                    acc[mi][ni] = __builtin_amdgcn_mfma_f32_16x16x32_bf16(
                        af[mi], bfr[ni], acc[mi][ni], 0, 0, 0);
        }
        __syncthreads();
    }

    // epilogue: C/D mapping col = lane&15, row = (lane>>4)*4 + reg  [m89]
    const int cq = lane >> 4;
    const int cc = lane & 15;
    #pragma unroll
    for (int mi = 0; mi < 4; ++mi) {
        #pragma unroll
        for (int ni = 0; ni < 4; ++ni) {
            const int col  = j0 + wn * 64 + ni * 16 + cc;
            const int rowb = i0 + wm * 64 + mi * 16 + cq * 4;
            #pragma unroll
            for (int v = 0; v < 4; ++v)
                S[(size_t)(rowb + v) * NROWS + col] = acc[mi][ni][v];
        }
    }
}

// per-row: Z, exact radix top-128 (smallest dots), masked accumulation
__global__ __launch_bounds__(256) void rowsel_kernel(
        const float* __restrict__ S,
        const float* __restrict__ sq,
        const unsigned char* __restrict__ lab8,
        float* __restrict__ out)
{
    __shared__ unsigned hist[256];
    __shared__ float    wred[4];
    __shared__ unsigned wscan0[4], wscan1[4];
    __shared__ unsigned selT, selK;
    __shared__ float    wsd[4];
    __shared__ int      wcnt[4];

    const int row  = blockIdx.x;
    const int tid  = threadIdx.x;
    const int lane = tid & 63;
    const int wv   = tid >> 6;

    // coalesced row load: j = c*1024 + tid*4 + e
    float d[4][4];
    const float4* S4 = (const float4*)(S + (size_t)row * NROWS);
    const float4* Q4 = (const float4*)sq;
    unsigned u[4][4];
    #pragma unroll
    for (int c = 0; c < 4; ++c) {
        float4 v = S4[c * 256 + tid];
        float4 q = Q4[c * 256 + tid];
        d[c][0] = v.x; d[c][1] = v.y; d[c][2] = v.z; d[c][3] = v.w;
        u[c][0] = fkey(fmaf(-2.f, v.x, q.x));
        u[c][1] = fkey(fmaf(-2.f, v.y, q.y));
        u[c][2] = fkey(fmaf(-2.f, v.z, q.z));
        u[c][3] = fkey(fmaf(-2.f, v.w, q.w));
    }

    // Z = sum_{j!=row} exp(10*dot)   (max-shift cancels algebraically)
    {
        float z = 0.f;
        #pragma unroll
        for (int c = 0; c < 4; ++c)
            #pragma unroll
            for (int e = 0; e < 4; ++e) {
                const int j = c * 1024 + tid * 4 + e;
                const float ex = __expf(10.f * d[c][e]);
                z += (j == row) ? 0.f : ex;
            }
        #pragma unroll
        for (int m = 1; m < 64; m <<= 1) z += __shfl_xor(z, m, 64);
        if (lane == 0) wred[wv] = z;
    }

    // radix-select the 128th-largest key
    unsigned P = 0, K = 128;
    #pragma unroll
    for (int pass = 0; pass < 4; ++pass) {
        const int shift = 24 - 8 * pass;
        hist[tid] = 0; __syncthreads();
        #pragma unroll
        for (int c = 0; c < 4; ++c)
            #pragma unroll
            for (int e = 0; e < 4; ++e) {
                const unsigned uu = u[c][e];
                const bool act = (pass == 0) ||
                                 ((uu >> (shift + 8)) == (P >> (shift + 8)));
                if (act) atomicAdd(&hist[(uu >> shift) & 255u], 1u);
            }
        __syncthreads();
        const unsigned g = hist[255 - tid];   // descending-bin suffix scan
        unsigned Pv = g;
        #pragma unroll
        for (int dd = 1; dd < 64; dd <<= 1) {
            const unsigned o = __shfl_up(Pv, dd, 64);
            if (lane >= dd) Pv += o;
        }
        if (lane == 63) wscan0[wv] = Pv;
        __syncthreads();
        unsigned off = 0;
        #pragma unroll
        for (int w = 0; w < 4; ++w) if (w < wv) off += wscan0[w];
        const unsigned Sv = Pv + off;
        const unsigned Sn = Sv - g;
        if (Sv >= K && Sn < K) {
            selT = P | ((unsigned)(255 - tid) << shift);
            selK = K - Sn;
        }
        __syncthreads();
        P = selT; K = selK;
        __syncthreads();
    }

    // tie ranks in ascending-j order: packed 16-bit per-c scan
    unsigned tc[4];
    #pragma unroll
    for (int c = 0; c < 4; ++c) {
        unsigned t = 0;
        #pragma unroll
        for (int e = 0; e < 4; ++e) t += (u[c][e] == P) ? 1u : 0u;
        tc[c] = t;
    }
    unsigned p0 = tc[0] | (tc[1] << 16);
    unsigned p1 = tc[2] | (tc[3] << 16);
    unsigned i0s = p0, i1s = p1;
    #pragma unroll
    for (int dd = 1; dd < 64; dd <<= 1) {
        const unsigned o0 = __shfl_up(i0s, dd, 64);
        const unsigned o1 = __shfl_up(i1s, dd, 64);
        if (lane >= dd) { i0s += o0; i1s += o1; }
    }
    if (lane == 63) { wscan0[wv] = i0s; wscan1[wv] = i1s; }
    __syncthreads();
    unsigned o0 = 0, o1 = 0;
    #pragma unroll
    for (int w = 0; w < 4; ++w) if (w < wv) { o0 += wscan0[w]; o1 += wscan1[w]; }
    i0s += o0; i1s += o1;                         // block-inclusive
    const unsigned g0 = wscan0[0] + wscan0[1] + wscan0[2] + wscan0[3];
    const unsigned g1 = wscan1[0] + wscan1[1] + wscan1[2] + wscan1[3];
    const unsigned tot0 = g0 & 0xFFFFu, tot1 = g0 >> 16, tot2 = g1 & 0xFFFFu;
    int trk[4];
    trk[0] = (int)((i0s & 0xFFFFu) - tc[0]);
    trk[1] = (int)(tot0 + (i0s >> 16) - tc[1]);
    trk[2] = (int)(tot0 + tot1 + (i1s & 0xFFFFu) - tc[2]);
    trk[3] = (int)(tot0 + tot1 + tot2 + (i1s >> 16) - tc[3]);

    // accumulate over selected & same-class & j != row
    const unsigned my = lab8[row];
    float sd = 0.f; int cnt = 0;
    #pragma unroll
    for (int c = 0; c < 4; ++c) {
        const unsigned lw = *(const unsigned*)(lab8 + c * 1024 + tid * 4);
        int t = trk[c];
        #pragma unroll
        for (int e = 0; e < 4; ++e) {
            const unsigned uu = u[c][e];
            bool sel = (uu > P);
            if (uu == P) { sel = (t < (int)K); t++; }
            const int j = c * 1024 + tid * 4 + e;
            const unsigned lj = (lw >> (8 * e)) & 255u;
            if (sel && j != row && lj == my) { cnt++; sd += d[c][e]; }
        }
    }
    #pragma unroll
    for (int m = 1; m < 64; m <<= 1) {
        sd  += __shfl_xor(sd, m, 64);
        cnt += __shfl_xor(cnt, m, 64);
    }
    if (lane == 0) { wsd[wv] = sd; wcnt[wv] = cnt; }
    __syncthreads();

    if (tid == 0) {
        const int c = wcnt[0] + wcnt[1] + wcnt[2] + wcnt[3];
        if (c > 0) {
            const float s = wsd[0] + wsd[1] + wsd[2] + wsd[3];
            const float Z = wred[0] + wred[1] + wred[2] + wred[3];
            const float mlpp = (10.f * s) / (float)c - __logf(Z);
            atomicAdd(out, -(0.1f / 0.07f) * mlpp * (1.f / (float)NROWS));
        }
    }
}

// ===========================================================================
// FALLBACK PATH (small d_ws): R2 fused kernels (verified correct)
// ===========================================================================

__global__ void prep_kernel(const float* __restrict__ feat,
                            const int* __restrict__ labels,
                            float* __restrict__ fn,
                            float* __restrict__ sq,
                            unsigned char* __restrict__ lab8,
                            float* __restrict__ out)
{
    const int row  = blockIdx.x * 4 + (threadIdx.x >> 6);
    const int lane = threadIdx.x & 63;
    float4 x = ((const float4*)feat)[(size_t)row * 64 + lane];
    float ss = x.x*x.x + x.y*x.y + x.z*x.z + x.w*x.w;
    #pragma unroll
    for (int m = 1; m < 64; m <<= 1) ss += __shfl_xor(ss, m, 64);
    const float nrm = sqrtf(ss);
    float4 f; f.x = x.x/nrm; f.y = x.y/nrm; f.z = x.z/nrm; f.w = x.w/nrm;
    ((float4*)fn)[(size_t)row * 64 + lane] = f;
    float s2 = f.x*f.x + f.y*f.y + f.z*f.z + f.w*f.w;
    #pragma unroll
    for (int m = 1; m < 64; m <<= 1) s2 += __shfl_xor(s2, m, 64);
    if (lane == 0) {
        sq[row]  = s2;
        lab8[row] = (unsigned char)labels[row & HALF_MASK];
    }
    if (blockIdx.x == 0 && threadIdx.x == 0) out[0] = 0.0f;
}

#define R 4
__global__ __launch_bounds__(BLOCK, 3) void rowloss_kernel(
        const float* __restrict__ fn,
        const float* __restrict__ sq,
        const unsigned char* __restrict__ lab8,
        float* __restrict__ out)
{
    __shared__ __align__(16) float fi[R][DIM];
    __shared__ unsigned hist[R * 256];
    __shared__ float    wz[R][4];
    __shared__ unsigned wsc[R][4];
    __shared__ unsigned selT[R], selK[R];
    __shared__ float    wsd[R][4];
    __shared__ int      wcnt[R][4];

    const int tid  = threadIdx.x;
    const int lane = tid & 63;
    const int wv   = tid >> 6;
    const int i0   = blockIdx.x * R;
    const int j0   = tid * 16;

    for (int idx = tid; idx < R * DIM; idx += BLOCK)
        fi[idx >> 8][idx & 255] = fn[(size_t)i0 * DIM + idx];
    __syncthreads();

    const float4* fn4 = (const float4*)fn;
    const float4* fi4 = (const float4*)&fi[0][0];

    float acc[16][R];
    #pragma unroll
    for (int jj = 0; jj < 16; ++jj)
        #pragma unroll
        for (int r = 0; r < R; ++r) acc[jj][r] = 0.0f;

    for (int c = 0; c < 32; ++c) {
        float fir[R][8];
        #pragma unroll
        for (int r = 0; r < R; ++r) {
            float4 a = fi4[r * 64 + c * 2];
            float4 b = fi4[r * 64 + c * 2 + 1];
            fir[r][0] = a.x; fir[r][1] = a.y; fir[r][2] = a.z; fir[r][3] = a.w;
            fir[r][4] = b.x; fir[r][5] = b.y; fir[r][6] = b.z; fir[r][7] = b.w;
        }
        #pragma unroll
        for (int jj = 0; jj < 16; ++jj) {
            const float4* p = fn4 + (size_t)(j0 + jj) * 64 + c * 2;
            float4 x = p[0];
            float4 y = p[1];
            #pragma unroll
            for (int r = 0; r < R; ++r) {
                float s = acc[jj][r];
                s = fmaf(x.x, fir[r][0], s); s = fmaf(x.y, fir[r][1], s);
                s = fmaf(x.z, fir[r][2], s); s = fmaf(x.w, fir[r][3], s);
                s = fmaf(y.x, fir[r][4], s); s = fmaf(y.y, fir[r][5], s);
                s = fmaf(y.z, fir[r][6], s); s = fmaf(y.w, fir[r][7], s);
                acc[jj][r] = s;
            }
        }
    }

    float sqr[16];
    #pragma unroll
    for (int k = 0; k < 16; ++k) sqr[k] = sq[j0 + k];

    float lzr[R];
    {
        float zloc[R];
        #pragma unroll
        for (int r = 0; r < R; ++r) {
            const int ir = i0 + r;
            float z = 0.0f;
            #pragma unroll
            for (int k = 0; k < 16; ++k) {
                float e = __expf(10.0f * acc[k][r]);
                z += (j0 + k == ir) ? 0.0f : e;
            }
            zloc[r] = z;
        }
        #pragma unroll
        for (int r = 0; r < R; ++r) {
            float z = zloc[r];
            #pragma unroll
            for (int m = 1; m < 64; m <<= 1) z += __shfl_xor(z, m, 64);
            if (lane == 0) wz[r][wv] = z;
        }
        __syncthreads();
        #pragma unroll
        for (int r = 0; r < R; ++r)
            lzr[r] = __logf(wz[r][0] + wz[r][1] + wz[r][2] + wz[r][3]);
    }

    unsigned Pr[R] = {0, 0, 0, 0};
    unsigned Kr[R] = {128u, 128u, 128u, 128u};
    #pragma unroll
    for (int pass = 0; pass < 4; ++pass) {
        const int shift = 24 - 8 * pass;
        #pragma unroll
        for (int r = 0; r < R; ++r) hist[r * 256 + tid] = 0u;
        __syncthreads();
        #pragma unroll
        for (int r = 0; r < R; ++r) {
            #pragma unroll
            for (int k = 0; k < 16; ++k) {
                unsigned uu = fkey(fmaf(-2.0f, acc[k][r], sqr[k]));
                bool act = (pass == 0) ||
                    (((unsigned long long)(uu ^ Pr[r]) >> (shift + 8)) == 0ull);
                if (act) atomicAdd(&hist[r * 256 + ((uu >> shift) & 255u)], 1u);
            }
        }
        __syncthreads();
        unsigned g[R], Pv[R];
        #pragma unroll
        for (int r = 0; r < R; ++r) { g[r] = hist[r * 256 + (255 - tid)]; Pv[r] = g[r]; }
        #pragma unroll
        for (int dd = 1; dd < 64; dd <<= 1) {
            #pragma unroll
            for (int r = 0; r < R; ++r) {
                unsigned o = __shfl_up(Pv[r], dd, 64);
                if (lane >= dd) Pv[r] += o;
            }
        }
        if (lane == 63) {
            #pragma unroll
            for (int r = 0; r < R; ++r) wsc[r][wv] = Pv[r];
        }
        __syncthreads();
        #pragma unroll
        for (int r = 0; r < R; ++r) {
            unsigned off = 0;
            #pragma unroll
            for (int w = 0; w < 4; ++w) if (w < wv) off += wsc[r][w];
            const unsigned Sv = Pv[r] + off;
            const unsigned Sn = Sv - g[r];
            if (Sv >= Kr[r] && Sn < Kr[r]) {
                selT[r] = Pr[r] | ((unsigned)(255 - tid) << shift);
                selK[r] = Kr[r] - Sn;
            }
        }
        __syncthreads();
        #pragma unroll
        for (int r = 0; r < R; ++r) { Pr[r] = selT[r]; Kr[r] = selK[r]; }
        __syncthreads();
    }

    int tb[R];
    {
        int tcr[R], Pt[R];
        #pragma unroll
        for (int r = 0; r < R; ++r) {
            int c = 0;
            #pragma unroll
            for (int k = 0; k < 16; ++k)
                if (fkey(fmaf(-2.0f, acc[k][r], sqr[k])) == Pr[r]) c++;
            tcr[r] = c; Pt[r] = c;
        }
        #pragma unroll
        for (int dd = 1; dd < 64; dd <<= 1) {
            #pragma unroll
            for (int r = 0; r < R; ++r) {
                int o = __shfl_up(Pt[r], dd, 64);
                if (lane >= dd) Pt[r] += o;
            }
        }
        if (lane == 63) {
            #pragma unroll
            for (int r = 0; r < R; ++r) wsc[r][wv] = (unsigned)Pt[r];
        }
        __syncthreads();
        #pragma unroll
        for (int r = 0; r < R; ++r) {
            int off = 0;
            #pragma unroll
            for (int w = 0; w < 4; ++w) if (w < wv) off += (int)wsc[r][w];
            tb[r] = Pt[r] + off - tcr[r];
        }
    }

    const uint4 labv = ((const uint4*)lab8)[tid];
    const unsigned labw[4] = {labv.x, labv.y, labv.z, labv.w};

    #pragma unroll
    for (int r = 0; r < R; ++r) {
        const int ir = i0 + r;
        const unsigned my = lab8[ir];
        float sd = 0.0f; int cnt = 0; int t = tb[r];
        #pragma unroll
        for (int k = 0; k < 16; ++k) {
            const unsigned uu = fkey(fmaf(-2.0f, acc[k][r], sqr[k]));
            bool sel = (uu > Pr[r]);
            if (uu == Pr[r]) { sel = (t < (int)Kr[r]); t++; }
            const unsigned lj = (labw[k >> 2] >> ((k & 3) * 8)) & 255u;
            if (sel && (j0 + k != ir) && lj == my) { cnt++; sd += acc[k][r]; }
        }
        #pragma unroll
        for (int m = 1; m < 64; m <<= 1) {
            sd  += __shfl_xor(sd, m, 64);
            cnt += __shfl_xor(cnt, m, 64);
        }
        if (lane == 0) { wsd[r][wv] = sd; wcnt[r][wv] = cnt; }
    }
    __syncthreads();

    if (tid < R) {
        const int r = tid;
        const int c = wcnt[r][0] + wcnt[r][1] + wcnt[r][2] + wcnt[r][3];
        if (c > 0) {
            const float sd = wsd[r][0] + wsd[r][1] + wsd[r][2] + wsd[r][3];
            const float mlpp = (10.0f * sd) / (float)c - lzr[r];
            atomicAdd(out, -(0.1f / 0.07f) * mlpp * (1.0f / (float)NROWS));
        }
    }
}

// ===========================================================================

extern "C" void kernel_launch(void* const* d_in, const int* in_sizes, int n_in,
                              void* d_out, int out_size, void* d_ws, size_t ws_size,
                              hipStream_t stream) {
    (void)in_sizes; (void)n_in; (void)out_size;
    const float* feat  = (const float*)d_in[0];
    const int* labels  = (const int*)d_in[1];
    float* out = (float*)d_out;

    // fast-path workspace layout
    const size_t offS = 0;                                   // 4096*4096 f32
    const size_t offF = (size_t)NROWS * NROWS * 4;           // fn bf16
    const size_t offQ = offF + (size_t)NROWS * DIM * 2;      // sq f32
    const size_t offL = offQ + (size_t)NROWS * 4;            // labels u8
    const size_t need = offL + (size_t)NROWS;

    if (ws_size >= need) {
        float* S   = (float*)((char*)d_ws + offS);
        short* fnb = (short*)((char*)d_ws + offF);
        float* sq  = (float*)((char*)d_ws + offQ);
        unsigned char* lab8 = (unsigned char*)((char*)d_ws + offL);

        prep_bf16_kernel<<<NROWS / 4, BLOCK, 0, stream>>>(feat, labels, fnb, sq, lab8, out);
        gram_kernel<<<(NROWS / 128) * (NROWS / 128), BLOCK, 0, stream>>>(fnb, S);
        rowsel_kernel<<<NROWS, BLOCK, 0, stream>>>(S, sq, lab8, out);
    } else {
        float* fn = (float*)d_ws;
        float* sq = fn + (size_t)NROWS * DIM;
        unsigned char* lab8 = (unsigned char*)(sq + NROWS);

        prep_kernel<<<NROWS / 4, BLOCK, 0, stream>>>(feat, labels, fn, sq, lab8, out);
        rowloss_kernel<<<NROWS / R, BLOCK, 0, stream>>>(fn, sq, lab8, out);
    }
}

// Round 4
// 96.537 us; speedup vs baseline: 6.9367x; 1.2711x over previous
//
#include <hip/hip_runtime.h>
#include <hip/hip_bf16.h>
#include <math.h>

#define NROWS 4096
#define DIM   256
#define HALF_MASK 2047
#define BLOCK 256

typedef __attribute__((ext_vector_type(8))) short bf16x8;
typedef __attribute__((ext_vector_type(4))) float f32x4;

// order-preserving float -> uint transform (ascending uint == ascending float)
__device__ __forceinline__ unsigned fkey(float f) {
    unsigned u = __float_as_uint(f);
    return (u & 0x80000000u) ? ~u : (u | 0x80000000u);
}

// ===========================================================================
// FAST PATH (needs ~68 MB of d_ws): prep -> bf16 MFMA Gram -> per-row select
// ===========================================================================

// prep: L2-normalize rows -> bf16 fn, fp32 sq, byte labels, zero out
__global__ void prep_bf16_kernel(const float* __restrict__ feat,
                                 const int* __restrict__ labels,
                                 short* __restrict__ fnb,
                                 float* __restrict__ sq,
                                 unsigned char* __restrict__ lab8,
                                 float* __restrict__ out)
{
    const int row  = blockIdx.x * 4 + (threadIdx.x >> 6);
    const int lane = threadIdx.x & 63;
    float4 x = ((const float4*)feat)[(size_t)row * 64 + lane];
    float ss = x.x*x.x + x.y*x.y + x.z*x.z + x.w*x.w;
    #pragma unroll
    for (int m = 1; m < 64; m <<= 1) ss += __shfl_xor(ss, m, 64);
    const float nrm = sqrtf(ss);
    float4 f; f.x = x.x/nrm; f.y = x.y/nrm; f.z = x.z/nrm; f.w = x.w/nrm;

    union { __hip_bfloat16 b; unsigned short s; } cv[4];
    cv[0].b = __float2bfloat16(f.x); cv[1].b = __float2bfloat16(f.y);
    cv[2].b = __float2bfloat16(f.z); cv[3].b = __float2bfloat16(f.w);
    ushort4 h; h.x = cv[0].s; h.y = cv[1].s; h.z = cv[2].s; h.w = cv[3].s;
    ((ushort4*)fnb)[(size_t)row * 64 + lane] = h;

    float s2 = f.x*f.x + f.y*f.y + f.z*f.z + f.w*f.w;
    #pragma unroll
    for (int m = 1; m < 64; m <<= 1) s2 += __shfl_xor(s2, m, 64);
    if (lane == 0) {
        sq[row]   = s2;
        lab8[row] = (unsigned char)labels[row & HALF_MASK];
    }
    if (blockIdx.x == 0 && threadIdx.x == 0) out[0] = 0.0f;
}

// Gram: S = fn * fn^T  (4096x4096, K=256), bf16 MFMA 16x16x32, fp32 out.
__global__ __launch_bounds__(256) void gram_kernel(
        const short* __restrict__ fnb, float* __restrict__ S)
{
    __shared__ __align__(16) short As[128 * 64];
    __shared__ __align__(16) short Bs[128 * 64];

    const int tid  = threadIdx.x;
    const int lane = tid & 63;
    const int wv   = tid >> 6;
    const int wm   = wv >> 1, wn = wv & 1;
    const int bi   = blockIdx.x >> 5;
    const int bj   = blockIdx.x & 31;
    const int i0   = bi * 128, j0 = bj * 128;

    f32x4 acc[4][4];
    const f32x4 zero = {0.f, 0.f, 0.f, 0.f};
    #pragma unroll
    for (int a = 0; a < 4; ++a)
        #pragma unroll
        for (int b = 0; b < 4; ++b) acc[a][b] = zero;

    const int srow   = tid >> 3;   // 0..31
    const int schunk = tid & 7;    // 0..7 (16B chunks of a 128B k-row)

    for (int kt = 0; kt < 4; ++kt) {         // K tiles of 64
        #pragma unroll
        for (int is = 0; is < 4; ++is) {
            const int row = is * 32 + srow;
            const size_t gsrc = (size_t)kt * 64 + schunk * 8;
            uint4 va = *(const uint4*)(fnb + (size_t)(i0 + row) * DIM + gsrc);
            uint4 vb = *(const uint4*)(fnb + (size_t)(j0 + row) * DIM + gsrc);
            const int dst = row * 64 + ((schunk ^ (row & 7)) * 8);
            *(uint4*)(As + dst) = va;
            *(uint4*)(Bs + dst) = vb;
        }
        __syncthreads();
        #pragma unroll
        for (int kk = 0; kk < 2; ++kk) {
            bf16x8 af[4], bfr[4];
            #pragma unroll
            for (int mi = 0; mi < 4; ++mi) {
                const int row = wm * 64 + mi * 16 + (lane & 15);
                const int ch  = kk * 4 + (lane >> 4);
                af[mi] = *(const bf16x8*)(As + row * 64 + ((ch ^ (row & 7)) * 8));
            }
            #pragma unroll
            for (int ni = 0; ni < 4; ++ni) {
                const int row = wn * 64 + ni * 16 + (lane & 15);
                const int ch  = kk * 4 + (lane >> 4);
                bfr[ni] = *(const bf16x8*)(Bs + row * 64 + ((ch ^ (row & 7)) * 8));
            }
            #pragma unroll
            for (int mi = 0; mi < 4; ++mi)
                #pragma unroll
                for (int ni = 0; ni < 4; ++ni)
                    acc[mi][ni] = __builtin_amdgcn_mfma_f32_16x16x32_bf16(
                        af[mi], bfr[ni], acc[mi][ni], 0, 0, 0);
        }
        __syncthreads();
    }

    // epilogue: C/D mapping col = lane&15, row = (lane>>4)*4 + reg  [m89]
    const int cq = lane >> 4;
    const int cc = lane & 15;
    #pragma unroll
    for (int mi = 0; mi < 4; ++mi) {
        #pragma unroll
        for (int ni = 0; ni < 4; ++ni) {
            const int col  = j0 + wn * 64 + ni * 16 + cc;
            const int rowb = i0 + wm * 64 + mi * 16 + cq * 4;
            #pragma unroll
            for (int v = 0; v < 4; ++v)
                S[(size_t)(rowb + v) * NROWS + col] = acc[mi][ni][v];
        }
    }
}

// per-row: Z, exact radix top-128 (smallest dots), masked accumulation.
// Histogram update uses a wave-uniform fast path: when all active lanes of a
// wave share the same digit (the common case in pass 0, where keys ~1.0 all
// map to top byte 0xBF), ONE leader atomic adds popcount(active) -- killing
// the 64-way same-bin LDS conflict storm.
__global__ __launch_bounds__(256) void rowsel_kernel(
        const float* __restrict__ S,
        const float* __restrict__ sq,
        const unsigned char* __restrict__ lab8,
        float* __restrict__ out)
{
    __shared__ unsigned hist[256];
    __shared__ float    wred[4];
    __shared__ unsigned wscan0[4], wscan1[4];
    __shared__ unsigned selT, selK;
    __shared__ float    wsd[4];
    __shared__ int      wcnt[4];

    const int row  = blockIdx.x;
    const int tid  = threadIdx.x;
    const int lane = tid & 63;
    const int wv   = tid >> 6;

    // coalesced row load: j = c*1024 + tid*4 + e
    float d[4][4];
    const float4* S4 = (const float4*)(S + (size_t)row * NROWS);
    const float4* Q4 = (const float4*)sq;
    unsigned u[4][4];
    #pragma unroll
    for (int c = 0; c < 4; ++c) {
        float4 v = S4[c * 256 + tid];
        float4 q = Q4[c * 256 + tid];
        d[c][0] = v.x; d[c][1] = v.y; d[c][2] = v.z; d[c][3] = v.w;
        u[c][0] = fkey(fmaf(-2.f, v.x, q.x));
        u[c][1] = fkey(fmaf(-2.f, v.y, q.y));
        u[c][2] = fkey(fmaf(-2.f, v.z, q.z));
        u[c][3] = fkey(fmaf(-2.f, v.w, q.w));
    }

    // Z = sum_{j!=row} exp(10*dot)   (max-shift cancels algebraically)
    {
        float z = 0.f;
        #pragma unroll
        for (int c = 0; c < 4; ++c)
            #pragma unroll
            for (int e = 0; e < 4; ++e) {
                const int j = c * 1024 + tid * 4 + e;
                const float ex = __expf(10.f * d[c][e]);
                z += (j == row) ? 0.f : ex;
            }
        #pragma unroll
        for (int m = 1; m < 64; m <<= 1) z += __shfl_xor(z, m, 64);
        if (lane == 0) wred[wv] = z;
    }

    // radix-select the 128th-largest key
    unsigned P = 0, K = 128;
    #pragma unroll
    for (int pass = 0; pass < 4; ++pass) {
        const int shift = 24 - 8 * pass;
        hist[tid] = 0; __syncthreads();
        #pragma unroll
        for (int c = 0; c < 4; ++c)
            #pragma unroll
            for (int e = 0; e < 4; ++e) {
                const unsigned uu = u[c][e];
                const bool act = (pass == 0) ||
                                 ((uu >> (shift + 8)) == (P >> (shift + 8)));
                const unsigned long long am = __ballot(act);
                if (am == 0ull) continue;                 // wave-uniform skip
                const unsigned dg = (uu >> shift) & 255u;
                const int fl = (int)(__ffsll((unsigned long long)am) - 1);
                const unsigned d0 = __builtin_amdgcn_readlane(dg, fl);
                const unsigned long long mm = __ballot(act && (dg == d0));
                if (mm == am) {                           // all active share d0
                    if (lane == fl) atomicAdd(&hist[d0], (unsigned)__popcll(am));
                } else {
                    if (act) atomicAdd(&hist[dg], 1u);
                }
            }
        __syncthreads();
        const unsigned g = hist[255 - tid];   // descending-bin suffix scan
        unsigned Pv = g;
        #pragma unroll
        for (int dd = 1; dd < 64; dd <<= 1) {
            const unsigned o = __shfl_up(Pv, dd, 64);
            if (lane >= dd) Pv += o;
        }
        if (lane == 63) wscan0[wv] = Pv;
        __syncthreads();
        unsigned off = 0;
        #pragma unroll
        for (int w = 0; w < 4; ++w) if (w < wv) off += wscan0[w];
        const unsigned Sv = Pv + off;
        const unsigned Sn = Sv - g;
        if (Sv >= K && Sn < K) {
            selT = P | ((unsigned)(255 - tid) << shift);
            selK = K - Sn;
        }
        __syncthreads();
        P = selT; K = selK;
        __syncthreads();
    }

    // tie ranks in ascending-j order: packed 16-bit per-c scan
    unsigned tc[4];
    #pragma unroll
    for (int c = 0; c < 4; ++c) {
        unsigned t = 0;
        #pragma unroll
        for (int e = 0; e < 4; ++e) t += (u[c][e] == P) ? 1u : 0u;
        tc[c] = t;
    }
    unsigned p0 = tc[0] | (tc[1] << 16);
    unsigned p1 = tc[2] | (tc[3] << 16);
    unsigned i0s = p0, i1s = p1;
    #pragma unroll
    for (int dd = 1; dd < 64; dd <<= 1) {
        const unsigned o0 = __shfl_up(i0s, dd, 64);
        const unsigned o1 = __shfl_up(i1s, dd, 64);
        if (lane >= dd) { i0s += o0; i1s += o1; }
    }
    if (lane == 63) { wscan0[wv] = i0s; wscan1[wv] = i1s; }
    __syncthreads();
    unsigned o0 = 0, o1 = 0;
    #pragma unroll
    for (int w = 0; w < 4; ++w) if (w < wv) { o0 += wscan0[w]; o1 += wscan1[w]; }
    i0s += o0; i1s += o1;                         // block-inclusive
    const unsigned g0 = wscan0[0] + wscan0[1] + wscan0[2] + wscan0[3];
    const unsigned g1 = wscan1[0] + wscan1[1] + wscan1[2] + wscan1[3];
    const unsigned tot0 = g0 & 0xFFFFu, tot1 = g0 >> 16, tot2 = g1 & 0xFFFFu;
    int trk[4];
    trk[0] = (int)((i0s & 0xFFFFu) - tc[0]);
    trk[1] = (int)(tot0 + (i0s >> 16) - tc[1]);
    trk[2] = (int)(tot0 + tot1 + (i1s & 0xFFFFu) - tc[2]);
    trk[3] = (int)(tot0 + tot1 + tot2 + (i1s >> 16) - tc[3]);

    // accumulate over selected & same-class & j != row
    const unsigned my = lab8[row];
    float sd = 0.f; int cnt = 0;
    #pragma unroll
    for (int c = 0; c < 4; ++c) {
        const unsigned lw = *(const unsigned*)(lab8 + c * 1024 + tid * 4);
        int t = trk[c];
        #pragma unroll
        for (int e = 0; e < 4; ++e) {
            const unsigned uu = u[c][e];
            bool sel = (uu > P);
            if (uu == P) { sel = (t < (int)K); t++; }
            const int j = c * 1024 + tid * 4 + e;
            const unsigned lj = (lw >> (8 * e)) & 255u;
            if (sel && j != row && lj == my) { cnt++; sd += d[c][e]; }
        }
    }
    #pragma unroll
    for (int m = 1; m < 64; m <<= 1) {
        sd  += __shfl_xor(sd, m, 64);
        cnt += __shfl_xor(cnt, m, 64);
    }
    if (lane == 0) { wsd[wv] = sd; wcnt[wv] = cnt; }
    __syncthreads();

    if (tid == 0) {
        const int c = wcnt[0] + wcnt[1] + wcnt[2] + wcnt[3];
        if (c > 0) {
            const float s = wsd[0] + wsd[1] + wsd[2] + wsd[3];
            const float Z = wred[0] + wred[1] + wred[2] + wred[3];
            const float mlpp = (10.f * s) / (float)c - __logf(Z);
            atomicAdd(out, -(0.1f / 0.07f) * mlpp * (1.f / (float)NROWS));
        }
    }
}

// ===========================================================================
// FALLBACK PATH (small d_ws): R2 fused kernels (verified correct)
// ===========================================================================

__global__ void prep_kernel(const float* __restrict__ feat,
                            const int* __restrict__ labels,
                            float* __restrict__ fn,
                            float* __restrict__ sq,
                            unsigned char* __restrict__ lab8,
                            float* __restrict__ out)
{
    const int row  = blockIdx.x * 4 + (threadIdx.x >> 6);
    const int lane = threadIdx.x & 63;
    float4 x = ((const float4*)feat)[(size_t)row * 64 + lane];
    float ss = x.x*x.x + x.y*x.y + x.z*x.z + x.w*x.w;
    #pragma unroll
    for (int m = 1; m < 64; m <<= 1) ss += __shfl_xor(ss, m, 64);
    const float nrm = sqrtf(ss);
    float4 f; f.x = x.x/nrm; f.y = x.y/nrm; f.z = x.z/nrm; f.w = x.w/nrm;
    ((float4*)fn)[(size_t)row * 64 + lane] = f;
    float s2 = f.x*f.x + f.y*f.y + f.z*f.z + f.w*f.w;
    #pragma unroll
    for (int m = 1; m < 64; m <<= 1) s2 += __shfl_xor(s2, m, 64);
    if (lane == 0) {
        sq[row]  = s2;
        lab8[row] = (unsigned char)labels[row & HALF_MASK];
    }
    if (blockIdx.x == 0 && threadIdx.x == 0) out[0] = 0.0f;
}

#define R 4
__global__ __launch_bounds__(BLOCK, 3) void rowloss_kernel(
        const float* __restrict__ fn,
        const float* __restrict__ sq,
        const unsigned char* __restrict__ lab8,
        float* __restrict__ out)
{
    __shared__ __align__(16) float fi[R][DIM];
    __shared__ unsigned hist[R * 256];
    __shared__ float    wz[R][4];
    __shared__ unsigned wsc[R][4];
    __shared__ unsigned selT[R], selK[R];
    __shared__ float    wsd[R][4];
    __shared__ int      wcnt[R][4];

    const int tid  = threadIdx.x;
    const int lane = tid & 63;
    const int wv   = tid >> 6;
    const int i0   = blockIdx.x * R;
    const int j0   = tid * 16;

    for (int idx = tid; idx < R * DIM; idx += BLOCK)
        fi[idx >> 8][idx & 255] = fn[(size_t)i0 * DIM + idx];
    __syncthreads();

    const float4* fn4 = (const float4*)fn;
    const float4* fi4 = (const float4*)&fi[0][0];

    float acc[16][R];
    #pragma unroll
    for (int jj = 0; jj < 16; ++jj)
        #pragma unroll
        for (int r = 0; r < R; ++r) acc[jj][r] = 0.0f;

    for (int c = 0; c < 32; ++c) {
        float fir[R][8];
        #pragma unroll
        for (int r = 0; r < R; ++r) {
            float4 a = fi4[r * 64 + c * 2];
            float4 b = fi4[r * 64 + c * 2 + 1];
            fir[r][0] = a.x; fir[r][1] = a.y; fir[r][2] = a.z; fir[r][3] = a.w;
            fir[r][4] = b.x; fir[r][5] = b.y; fir[r][6] = b.z; fir[r][7] = b.w;
        }
        #pragma unroll
        for (int jj = 0; jj < 16; ++jj) {
            const float4* p = fn4 + (size_t)(j0 + jj) * 64 + c * 2;
            float4 x = p[0];
            float4 y = p[1];
            #pragma unroll
            for (int r = 0; r < R; ++r) {
                float s = acc[jj][r];
                s = fmaf(x.x, fir[r][0], s); s = fmaf(x.y, fir[r][1], s);
                s = fmaf(x.z, fir[r][2], s); s = fmaf(x.w, fir[r][3], s);
                s = fmaf(y.x, fir[r][4], s); s = fmaf(y.y, fir[r][5], s);
                s = fmaf(y.z, fir[r][6], s); s = fmaf(y.w, fir[r][7], s);
                acc[jj][r] = s;
            }
        }
    }

    float sqr[16];
    #pragma unroll
    for (int k = 0; k < 16; ++k) sqr[k] = sq[j0 + k];

    float lzr[R];
    {
        float zloc[R];
        #pragma unroll
        for (int r = 0; r < R; ++r) {
            const int ir = i0 + r;
            float z = 0.0f;
            #pragma unroll
            for (int k = 0; k < 16; ++k) {
                float e = __expf(10.0f * acc[k][r]);
                z += (j0 + k == ir) ? 0.0f : e;
            }
            zloc[r] = z;
        }
        #pragma unroll
        for (int r = 0; r < R; ++r) {
            float z = zloc[r];
            #pragma unroll
            for (int m = 1; m < 64; m <<= 1) z += __shfl_xor(z, m, 64);
            if (lane == 0) wz[r][wv] = z;
        }
        __syncthreads();
        #pragma unroll
        for (int r = 0; r < R; ++r)
            lzr[r] = __logf(wz[r][0] + wz[r][1] + wz[r][2] + wz[r][3]);
    }

    unsigned Pr[R] = {0, 0, 0, 0};
    unsigned Kr[R] = {128u, 128u, 128u, 128u};
    #pragma unroll
    for (int pass = 0; pass < 4; ++pass) {
        const int shift = 24 - 8 * pass;
        #pragma unroll
        for (int r = 0; r < R; ++r) hist[r * 256 + tid] = 0u;
        __syncthreads();
        #pragma unroll
        for (int r = 0; r < R; ++r) {
            #pragma unroll
            for (int k = 0; k < 16; ++k) {
                unsigned uu = fkey(fmaf(-2.0f, acc[k][r], sqr[k]));
                bool act = (pass == 0) ||
                    (((unsigned long long)(uu ^ Pr[r]) >> (shift + 8)) == 0ull);
                if (act) atomicAdd(&hist[r * 256 + ((uu >> shift) & 255u)], 1u);
            }
        }
        __syncthreads();
        unsigned g[R], Pv[R];
        #pragma unroll
        for (int r = 0; r < R; ++r) { g[r] = hist[r * 256 + (255 - tid)]; Pv[r] = g[r]; }
        #pragma unroll
        for (int dd = 1; dd < 64; dd <<= 1) {
            #pragma unroll
            for (int r = 0; r < R; ++r) {
                unsigned o = __shfl_up(Pv[r], dd, 64);
                if (lane >= dd) Pv[r] += o;
            }
        }
        if (lane == 63) {
            #pragma unroll
            for (int r = 0; r < R; ++r) wsc[r][wv] = Pv[r];
        }
        __syncthreads();
        #pragma unroll
        for (int r = 0; r < R; ++r) {
            unsigned off = 0;
            #pragma unroll
            for (int w = 0; w < 4; ++w) if (w < wv) off += wsc[r][w];
            const unsigned Sv = Pv[r] + off;
            const unsigned Sn = Sv - g[r];
            if (Sv >= Kr[r] && Sn < Kr[r]) {
                selT[r] = Pr[r] | ((unsigned)(255 - tid) << shift);
                selK[r] = Kr[r] - Sn;
            }
        }
        __syncthreads();
        #pragma unroll
        for (int r = 0; r < R; ++r) { Pr[r] = selT[r]; Kr[r] = selK[r]; }
        __syncthreads();
    }

    int tb[R];
    {
        int tcr[R], Pt[R];
        #pragma unroll
        for (int r = 0; r < R; ++r) {
            int c = 0;
            #pragma unroll
            for (int k = 0; k < 16; ++k)
                if (fkey(fmaf(-2.0f, acc[k][r], sqr[k])) == Pr[r]) c++;
            tcr[r] = c; Pt[r] = c;
        }
        #pragma unroll
        for (int dd = 1; dd < 64; dd <<= 1) {
            #pragma unroll
            for (int r = 0; r < R; ++r) {
                int o = __shfl_up(Pt[r], dd, 64);
                if (lane >= dd) Pt[r] += o;
            }
        }
        if (lane == 63) {
            #pragma unroll
            for (int r = 0; r < R; ++r) wsc[r][wv] = (unsigned)Pt[r];
        }
        __syncthreads();
        #pragma unroll
        for (int r = 0; r < R; ++r) {
            int off = 0;
            #pragma unroll
            for (int w = 0; w < 4; ++w) if (w < wv) off += (int)wsc[r][w];
            tb[r] = Pt[r] + off - tcr[r];
        }
    }

    const uint4 labv = ((const uint4*)lab8)[tid];
    const unsigned labw[4] = {labv.x, labv.y, labv.z, labv.w};

    #pragma unroll
    for (int r = 0; r < R; ++r) {
        const int ir = i0 + r;
        const unsigned my = lab8[ir];
        float sd = 0.0f; int cnt = 0; int t = tb[r];
        #pragma unroll
        for (int k = 0; k < 16; ++k) {
            const unsigned uu = fkey(fmaf(-2.0f, acc[k][r], sqr[k]));
            bool sel = (uu > Pr[r]);
            if (uu == Pr[r]) { sel = (t < (int)Kr[r]); t++; }
            const unsigned lj = (labw[k >> 2] >> ((k & 3) * 8)) & 255u;
            if (sel && (j0 + k != ir) && lj == my) { cnt++; sd += acc[k][r]; }
        }
        #pragma unroll
        for (int m = 1; m < 64; m <<= 1) {
            sd  += __shfl_xor(sd, m, 64);
            cnt += __shfl_xor(cnt, m, 64);
        }
        if (lane == 0) { wsd[r][wv] = sd; wcnt[r][wv] = cnt; }
    }
    __syncthreads();

    if (tid < R) {
        const int r = tid;
        const int c = wcnt[r][0] + wcnt[r][1] + wcnt[r][2] + wcnt[r][3];
        if (c > 0) {
            const float sd = wsd[r][0] + wsd[r][1] + wsd[r][2] + wsd[r][3];
            const float mlpp = (10.0f * sd) / (float)c - lzr[r];
            atomicAdd(out, -(0.1f / 0.07f) * mlpp * (1.0f / (float)NROWS));
        }
    }
}

// ===========================================================================

extern "C" void kernel_launch(void* const* d_in, const int* in_sizes, int n_in,
                              void* d_out, int out_size, void* d_ws, size_t ws_size,
                              hipStream_t stream) {
    (void)in_sizes; (void)n_in; (void)out_size;
    const float* feat  = (const float*)d_in[0];
    const int* labels  = (const int*)d_in[1];
    float* out = (float*)d_out;

    // fast-path workspace layout
    const size_t offS = 0;                                   // 4096*4096 f32
    const size_t offF = (size_t)NROWS * NROWS * 4;           // fn bf16
    const size_t offQ = offF + (size_t)NROWS * DIM * 2;      // sq f32
    const size_t offL = offQ + (size_t)NROWS * 4;            // labels u8
    const size_t need = offL + (size_t)NROWS;

    if (ws_size >= need) {
        float* S   = (float*)((char*)d_ws + offS);
        short* fnb = (short*)((char*)d_ws + offF);
        float* sq  = (float*)((char*)d_ws + offQ);
        unsigned char* lab8 = (unsigned char*)((char*)d_ws + offL);

        prep_bf16_kernel<<<NROWS / 4, BLOCK, 0, stream>>>(feat, labels, fnb, sq, lab8, out);
        gram_kernel<<<(NROWS / 128) * (NROWS / 128), BLOCK, 0, stream>>>(fnb, S);
        rowsel_kernel<<<NROWS, BLOCK, 0, stream>>>(S, sq, lab8, out);
    } else {
        float* fn = (float*)d_ws;
        float* sq = fn + (size_t)NROWS * DIM;
        unsigned char* lab8 = (unsigned char*)(sq + NROWS);

        prep_kernel<<<NROWS / 4, BLOCK, 0, stream>>>(feat, labels, fn, sq, lab8, out);
        rowloss_kernel<<<NROWS / R, BLOCK, 0, stream>>>(fn, sq, lab8, out);
    }
}